// Round 1
// baseline (3180.568 us; speedup 1.0000x reference)
//
#include <hip/hip_runtime.h>

// CG-SENSE: B=4, C=16, H=W=384. All fp32. x lives directly in d_out (float2 == [.,2]).
// ws layout: tmp[B*C*H*W] float2 (75.5MB) | r | p | Ap (4.7MB each) | scalars (rTr[11][B], pAp[10][B])
// Total ws needed ~89.7 MB.

#define Bn 4
#define Cn 16
#define Hn 384
#define Wn 384
#define NPIX (Hn*Wn)
#define TPB 256
#define NROW 8
#define PITCH 385
#define TOLF 1e-10f
#define NITER 10
#define RED_BLKS 72   // 72*256*8 == NPIX exactly

__device__ __forceinline__ float2 cmulf(float2 a, float2 b){
  return make_float2(a.x*b.x - a.y*b.y, a.x*b.y + a.y*b.x);
}

// ---------------- mixed-radix Stockham DIF, N=384 = 4*4*4*2*3 ----------------
// Generic DIF stage: y[q + s*(r*p + j)] = (sum_t x[q + s*(p + t*m)] * w_r^{jt}) * w_n^{pj}
// radix-4 stages all have s*m = 96; butterfly count N/4 = 96 (3 per lane, 32 lanes/row).

template<int DIR, int S, int N>
__device__ __forceinline__ void radix4_stage(const float2* __restrict__ X, float2* __restrict__ Y, int lane)
{
  const float theta = (float)DIR * 6.2831853071795864769f / (float)N;
#pragma unroll
  for (int k = 0; k < 3; ++k) {
    int u = lane + 32*k;
    int p = u / S;
    int q = u - p*S;
    float2 a0 = X[u], a1 = X[u+96], a2 = X[u+192], a3 = X[u+288];
    float2 t0 = make_float2(a0.x+a2.x, a0.y+a2.y);
    float2 t1 = make_float2(a0.x-a2.x, a0.y-a2.y);
    float2 t2 = make_float2(a1.x+a3.x, a1.y+a3.y);
    float2 t3 = make_float2(a1.x-a3.x, a1.y-a3.y);
    float2 b0 = make_float2(t0.x+t2.x, t0.y+t2.y);
    float2 b2 = make_float2(t0.x-t2.x, t0.y-t2.y);
    float2 b1, b3;
    if (DIR < 0) {  // forward: w4 = -i
      b1 = make_float2(t1.x + t3.y, t1.y - t3.x);
      b3 = make_float2(t1.x - t3.y, t1.y + t3.x);
    } else {
      b1 = make_float2(t1.x - t3.y, t1.y + t3.x);
      b3 = make_float2(t1.x + t3.y, t1.y - t3.x);
    }
    float sn, cn;
    __sincosf(theta * (float)p, &sn, &cn);
    float2 w1 = make_float2(cn, sn);
    float2 w2 = cmulf(w1, w1);
    float2 w3 = cmulf(w2, w1);
    int base = 4*u - 3*q;
    Y[base]       = b0;
    Y[base + S]   = cmulf(b1, w1);
    Y[base + 2*S] = cmulf(b2, w2);
    Y[base + 3*S] = cmulf(b3, w3);
  }
}

template<int DIR>
__device__ __forceinline__ void radix2_stage(const float2* __restrict__ X, float2* __restrict__ Y, int lane)
{
  // n=6, s=64, m=3: 192 butterflies
  const float theta = (float)DIR * 6.2831853071795864769f / 6.0f;
#pragma unroll
  for (int k = 0; k < 6; ++k) {
    int u = lane + 32*k;
    int p = u >> 6;
    int q = u & 63;
    float2 a0 = X[u], a1 = X[u+192];
    float2 b0 = make_float2(a0.x+a1.x, a0.y+a1.y);
    float2 d  = make_float2(a0.x-a1.x, a0.y-a1.y);
    float sn, cn;
    __sincosf(theta * (float)p, &sn, &cn);
    int base = 2*u - q;
    Y[base]      = b0;
    Y[base + 64] = cmulf(d, make_float2(cn, sn));
  }
}

template<int DIR>
__device__ __forceinline__ void radix3_stage(const float2* __restrict__ X, float2* __restrict__ Y, int lane)
{
  // n=3, s=128, m=1, p=0 (twiddle-free): 128 butterflies
  const float SQ = (DIR < 0) ? -0.86602540378443864676f : 0.86602540378443864676f;
#pragma unroll
  for (int k = 0; k < 4; ++k) {
    int u = lane + 32*k;
    float2 a0 = X[u], a1 = X[u+128], a2 = X[u+256];
    float2 s12 = make_float2(a1.x+a2.x, a1.y+a2.y);
    float2 d12 = make_float2(a1.x-a2.x, a1.y-a2.y);
    float2 b0 = make_float2(a0.x+s12.x, a0.y+s12.y);
    float2 mm = make_float2(a0.x-0.5f*s12.x, a0.y-0.5f*s12.y);
    float2 e  = make_float2(-d12.y*SQ, d12.x*SQ);
    Y[u]     = b0;
    Y[u+128] = make_float2(mm.x+e.x, mm.y+e.y);
    Y[u+256] = make_float2(mm.x-e.x, mm.y-e.y);
  }
}

// Runs all 5 stages X->Y->X->Y->X->Y. Result in Y. Contains __syncthreads (uniform).
template<int DIR>
__device__ __forceinline__ void fft_stages(float2* Xr, float2* Yr, int lane)
{
  radix4_stage<DIR, 1, 384>(Xr, Yr, lane); __syncthreads();
  radix4_stage<DIR, 4,  96>(Yr, Xr, lane); __syncthreads();
  radix4_stage<DIR,16,  24>(Xr, Yr, lane); __syncthreads();
  radix2_stage<DIR>(Yr, Xr, lane);         __syncthreads();
  radix3_stage<DIR>(Xr, Yr, lane);         __syncthreads();
}

// ---------------- FFT kernels ----------------

// K1: tmp[b,c,h,:] = FFT_w( S[b,c,h,:] * p[b,h,:] )
__global__ __launch_bounds__(TPB) void k_row_fwd(
    const float2* __restrict__ p, const float* __restrict__ Sre,
    const float* __restrict__ Sim, float2* __restrict__ tmp)
{
  __shared__ float2 bufA[NROW*PITCH];
  __shared__ float2 bufB[NROW*PITCH];
  int tid = threadIdx.x;
  int tile = blockIdx.x % (Hn/NROW);
  int bc   = blockIdx.x / (Hn/NROW);
  int b = bc / Cn;
  int h0 = tile * NROW;
  for (int e = tid; e < NROW*Wn; e += TPB) {
    int r = e / Wn, col = e - r*Wn;
    int gi = (h0 + r)*Wn + col;
    float2 pv = p[b*NPIX + gi];
    float sr = Sre[(size_t)bc*NPIX + gi], si = Sim[(size_t)bc*NPIX + gi];
    bufA[r*PITCH + col] = make_float2(sr*pv.x - si*pv.y, sr*pv.y + si*pv.x);
  }
  __syncthreads();
  int row = tid >> 5, lane = tid & 31;
  fft_stages<-1>(bufA + row*PITCH, bufB + row*PITCH, lane);
  for (int e = tid; e < NROW*Wn; e += TPB) {
    int r = e / Wn, col = e - r*Wn;
    tmp[(size_t)bc*NPIX + (h0 + r)*Wn + col] = bufB[r*PITCH + col];
  }
}

// K2: column FFTs on an 8-column tile. FULL: fwd + mask*(1/(H*W)) + inv. else: inv only.
template<bool FULL>
__global__ __launch_bounds__(TPB) void k_col(
    float2* __restrict__ tmp, const float* __restrict__ mask)
{
  __shared__ float2 bufA[NROW*PITCH];
  __shared__ float2 bufB[NROW*PITCH];
  int tid = threadIdx.x;
  int tile = blockIdx.x % (Wn/NROW);
  int bc   = blockIdx.x / (Wn/NROW);
  int b = bc / Cn;
  int w0 = tile * NROW;
  for (int e = tid; e < NROW*Hn; e += TPB) {
    int wi = e & 7, h = e >> 3;
    bufA[wi*PITCH + h] = tmp[(size_t)bc*NPIX + h*Wn + w0 + wi];
  }
  __syncthreads();
  int row = tid >> 5, lane = tid & 31;
  float2* X = bufA + row*PITCH;
  float2* Y = bufB + row*PITCH;
  if (FULL) {
    fft_stages<-1>(X, Y, lane);                  // result in bufB
    const float SC = 1.0f / (float)NPIX;
    for (int e = tid; e < NROW*Hn; e += TPB) {
      int wi = e & 7, h = e >> 3;
      float mv = mask[b*NPIX + h*Wn + w0 + wi] * SC;
      float2 v = bufB[wi*PITCH + h];
      bufB[wi*PITCH + h] = make_float2(v.x*mv, v.y*mv);
    }
    __syncthreads();
    fft_stages<1>(Y, X, lane);                   // result in bufA
    for (int e = tid; e < NROW*Hn; e += TPB) {
      int wi = e & 7, h = e >> 3;
      tmp[(size_t)bc*NPIX + h*Wn + w0 + wi] = bufA[wi*PITCH + h];
    }
  } else {
    fft_stages<1>(X, Y, lane);                   // result in bufB
    for (int e = tid; e < NROW*Hn; e += TPB) {
      int wi = e & 7, h = e >> 3;
      tmp[(size_t)bc*NPIX + h*Wn + w0 + wi] = bufB[wi*PITCH + h];
    }
  }
}

// K3: out[b] += conj(S[b,c]) * IFFT_w(tmp[b,c]) ; out pre-initialized to lambda*base.
__global__ __launch_bounds__(TPB) void k_row_inv_red(
    const float2* __restrict__ tmp, const float* __restrict__ Sre,
    const float* __restrict__ Sim, float* __restrict__ outAcc)
{
  __shared__ float2 bufA[NROW*PITCH];
  __shared__ float2 bufB[NROW*PITCH];
  int tid = threadIdx.x;
  int tile = blockIdx.x % (Hn/NROW);
  int bc   = blockIdx.x / (Hn/NROW);
  int b = bc / Cn;
  int h0 = tile * NROW;
  for (int e = tid; e < NROW*Wn; e += TPB) {
    int r = e / Wn, col = e - r*Wn;
    bufA[r*PITCH + col] = tmp[(size_t)bc*NPIX + (h0 + r)*Wn + col];
  }
  __syncthreads();
  int row = tid >> 5, lane = tid & 31;
  fft_stages<1>(bufA + row*PITCH, bufB + row*PITCH, lane);
  for (int e = tid; e < NROW*Wn; e += TPB) {
    int r = e / Wn, col = e - r*Wn;
    int gi = (h0 + r)*Wn + col;
    float2 v = bufB[r*PITCH + col];
    float sr = Sre[(size_t)bc*NPIX + gi], si = Sim[(size_t)bc*NPIX + gi];
    unsafeAtomicAdd(&outAcc[2*((size_t)b*NPIX + gi)],     sr*v.x + si*v.y);
    unsafeAtomicAdd(&outAcc[2*((size_t)b*NPIX + gi) + 1], sr*v.y - si*v.x);
  }
}

// ---------------- elementwise / CG kernels ----------------

__global__ __launch_bounds__(TPB) void k_pre(
    const float* __restrict__ yre, const float* __restrict__ yim,
    const float* __restrict__ mask, float2* __restrict__ tmp)
{
  size_t i = (size_t)blockIdx.x*TPB + threadIdx.x;
  if (i >= (size_t)Bn*Cn*NPIX) return;
  size_t bc = i / NPIX; size_t b = bc / Cn; size_t pix = i - bc*NPIX;
  float m = mask[b*NPIX + pix] * (1.0f/384.0f);
  tmp[i] = make_float2(yre[i]*m, yim[i]*m);
}

__global__ __launch_bounds__(TPB) void k_lam_planes(
    const float* __restrict__ xre, const float* __restrict__ xim,
    const float* __restrict__ lam, float2* __restrict__ out)
{
  size_t i = (size_t)blockIdx.x*TPB + threadIdx.x;
  if (i >= (size_t)Bn*NPIX) return;
  float l = lam[0];
  out[i] = make_float2(l*xre[i], l*xim[i]);
}

__global__ __launch_bounds__(TPB) void k_lam_vec(
    const float2* __restrict__ p, const float* __restrict__ lam, float2* __restrict__ Ap)
{
  size_t i = (size_t)blockIdx.x*TPB + threadIdx.x;
  if (i >= (size_t)Bn*NPIX) return;
  float l = lam[0];
  float2 pv = p[i];
  Ap[i] = make_float2(l*pv.x, l*pv.y);
}

__global__ void k_zero_scal(float* __restrict__ scal)
{
  int i = threadIdx.x;
  if (i < 96) scal[i] = 0.0f;
}

__device__ __forceinline__ void block_reduce_atomic(float sum, float* target)
{
  __shared__ float red[TPB];
  red[threadIdx.x] = sum; __syncthreads();
  for (int s = TPB/2; s > 0; s >>= 1) {
    if (threadIdx.x < s) red[threadIdx.x] += red[threadIdx.x + s];
    __syncthreads();
  }
  if (threadIdx.x == 0) unsafeAtomicAdd(target, red[0]);
}

// x=0, p=r, rTr0 = sum|r|^2
__global__ __launch_bounds__(TPB) void k_cg_init(
    const float2* __restrict__ r, float2* __restrict__ x, float2* __restrict__ p,
    float* __restrict__ scal)
{
  int b = blockIdx.y;
  float sum = 0.0f;
  for (int i = blockIdx.x*TPB + threadIdx.x; i < NPIX; i += RED_BLKS*TPB) {
    float2 rv = r[(size_t)b*NPIX + i];
    x[(size_t)b*NPIX + i] = make_float2(0.0f, 0.0f);
    p[(size_t)b*NPIX + i] = rv;
    sum += rv.x*rv.x + rv.y*rv.y;
  }
  block_reduce_atomic(sum, &scal[b]);
}

__global__ __launch_bounds__(TPB) void k_dot(
    const float2* __restrict__ p, const float2* __restrict__ Ap, float* __restrict__ slot)
{
  int b = blockIdx.y;
  float sum = 0.0f;
  for (int i = blockIdx.x*TPB + threadIdx.x; i < NPIX; i += RED_BLKS*TPB) {
    float2 a = p[(size_t)b*NPIX + i], c = Ap[(size_t)b*NPIX + i];
    sum += a.x*c.x + a.y*c.y;
  }
  block_reduce_atomic(sum, &slot[b]);
}

// x += alpha p; r -= alpha Ap; rTr_new = sum|r|^2  (frozen if rTr <= TOL)
__global__ __launch_bounds__(TPB) void k_upd1(
    float2* __restrict__ x, float2* __restrict__ r,
    const float2* __restrict__ p, const float2* __restrict__ Ap,
    const float* __restrict__ rtr_cur, float* __restrict__ rtr_new,
    const float* __restrict__ pap)
{
  int b = blockIdx.y;
  float rtr = rtr_cur[b];
  bool act = rtr > TOLF;
  float alpha = act ? rtr / pap[b] : 0.0f;
  float sum = 0.0f;
  for (int i = blockIdx.x*TPB + threadIdx.x; i < NPIX; i += RED_BLKS*TPB) {
    size_t gi = (size_t)b*NPIX + i;
    float2 rv = r[gi];
    if (act) {
      float2 pv = p[gi], av = Ap[gi], xv = x[gi];
      xv.x += alpha*pv.x; xv.y += alpha*pv.y;
      rv.x -= alpha*av.x; rv.y -= alpha*av.y;
      x[gi] = xv; r[gi] = rv;
    }
    sum += rv.x*rv.x + rv.y*rv.y;
  }
  block_reduce_atomic(sum, &rtr_new[b]);
}

// p = r + beta p (if active); Ap = lambda*p (pre-init for next iteration)
__global__ __launch_bounds__(TPB) void k_upd2(
    float2* __restrict__ p, const float2* __restrict__ r, float2* __restrict__ Ap,
    const float* __restrict__ lam,
    const float* __restrict__ rtr_cur, const float* __restrict__ rtr_new)
{
  int b = blockIdx.y;
  float rtr = rtr_cur[b];
  bool act = rtr > TOLF;
  float beta = act ? rtr_new[b] / rtr : 0.0f;
  float l = lam[0];
  for (int i = blockIdx.x*TPB + threadIdx.x; i < NPIX; i += RED_BLKS*TPB) {
    size_t gi = (size_t)b*NPIX + i;
    float2 pv = p[gi];
    if (act) {
      float2 rv = r[gi];
      pv = make_float2(rv.x + beta*pv.x, rv.y + beta*pv.y);
      p[gi] = pv;
    }
    Ap[gi] = make_float2(l*pv.x, l*pv.y);
  }
}

// ---------------- launch ----------------

extern "C" void kernel_launch(void* const* d_in, const int* in_sizes, int n_in,
                              void* d_out, int out_size, void* d_ws, size_t ws_size,
                              hipStream_t stream)
{
  const float* lam  = (const float*)d_in[0];
  const float* xre  = (const float*)d_in[1];
  const float* xim  = (const float*)d_in[2];
  const float* yre  = (const float*)d_in[3];
  const float* yim  = (const float*)d_in[4];
  const float* sre  = (const float*)d_in[5];
  const float* sim  = (const float*)d_in[6];
  const float* mask = (const float*)d_in[7];

  char* ws = (char*)d_ws;
  float2* tmp = (float2*)ws;  ws += (size_t)Bn*Cn*NPIX*sizeof(float2);
  float2* r   = (float2*)ws;  ws += (size_t)Bn*NPIX*sizeof(float2);
  float2* p   = (float2*)ws;  ws += (size_t)Bn*NPIX*sizeof(float2);
  float2* Ap  = (float2*)ws;  ws += (size_t)Bn*NPIX*sizeof(float2);
  float*  scal= (float*)ws;   // rTr[11][B] at [0..43], pAp[10][B] at [44..83]
  float2* x   = (float2*)d_out;

  dim3 blk(TPB);
  dim3 rg(RED_BLKS, Bn);
  int grid_fft_row = Bn*Cn*(Hn/NROW);   // 3072
  int grid_fft_col = Bn*Cn*(Wn/NROW);   // 3072

  k_zero_scal<<<1, 128, 0, stream>>>(scal);

  // ---- rhs = AH(y) + lambda*x  (into r) ----
  k_pre<<<(Bn*Cn*NPIX)/TPB, blk, 0, stream>>>(yre, yim, mask, tmp);
  k_col<false><<<grid_fft_col, blk, 0, stream>>>(tmp, mask);
  k_lam_planes<<<(Bn*NPIX)/TPB, blk, 0, stream>>>(xre, xim, lam, r);
  k_row_inv_red<<<grid_fft_row, blk, 0, stream>>>(tmp, sre, sim, (float*)r);

  // ---- CG init: x=0, p=r, rTr0 ----
  k_cg_init<<<rg, blk, 0, stream>>>(r, x, p, scal);
  k_lam_vec<<<(Bn*NPIX)/TPB, blk, 0, stream>>>(p, lam, Ap);

  for (int it = 0; it < NITER; ++it) {
    k_row_fwd<<<grid_fft_row, blk, 0, stream>>>(p, sre, sim, tmp);
    k_col<true><<<grid_fft_col, blk, 0, stream>>>(tmp, mask);
    k_row_inv_red<<<grid_fft_row, blk, 0, stream>>>(tmp, sre, sim, (float*)Ap);
    k_dot<<<rg, blk, 0, stream>>>(p, Ap, scal + 44 + it*Bn);
    k_upd1<<<rg, blk, 0, stream>>>(x, r, p, Ap, scal + it*Bn, scal + (it+1)*Bn, scal + 44 + it*Bn);
    if (it < NITER-1)
      k_upd2<<<rg, blk, 0, stream>>>(p, r, Ap, lam, scal + it*Bn, scal + (it+1)*Bn);
  }
}

// Round 2
// 2590.169 us; speedup vs baseline: 1.2279x; 1.2279x over previous
//
#include <hip/hip_runtime.h>

// CG-SENSE: B=4, C=16, H=W=384. All fp32. x lives directly in d_out (float2 == [.,2]).
// ws layout: tmp[B*C*NPIX] float2 (75.5MB) | partial[G*B*NPIX] float2 (18.9MB)
//            | r | p | Ap (4.7MB each) | scalars (rTr[11][B], pAp[10][B])

#define Bn 4
#define Cn 16
#define Hn 384
#define Wn 384
#define NPIX (Hn*Wn)
#define TPB 256
#define NROW 8
#define PITCH 385
#define TOLF 1e-10f
#define NITER 10
#define RED_BLKS 72   // 72*256*8 == NPIX exactly
#define GRP 4         // coil groups for atomic-free reduction
#define CPG (Cn/GRP)  // coils per group = 4

__device__ __forceinline__ float2 cmulf(float2 a, float2 b){
  return make_float2(a.x*b.x - a.y*b.y, a.x*b.y + a.y*b.x);
}

// ---------------- mixed-radix Stockham DIF, N=384 = 4*4*4*2*3 ----------------

template<int DIR, int S, int N>
__device__ __forceinline__ void radix4_stage(const float2* __restrict__ X, float2* __restrict__ Y, int lane)
{
  const float theta = (float)DIR * 6.2831853071795864769f / (float)N;
#pragma unroll
  for (int k = 0; k < 3; ++k) {
    int u = lane + 32*k;
    int p = u / S;
    int q = u - p*S;
    float2 a0 = X[u], a1 = X[u+96], a2 = X[u+192], a3 = X[u+288];
    float2 t0 = make_float2(a0.x+a2.x, a0.y+a2.y);
    float2 t1 = make_float2(a0.x-a2.x, a0.y-a2.y);
    float2 t2 = make_float2(a1.x+a3.x, a1.y+a3.y);
    float2 t3 = make_float2(a1.x-a3.x, a1.y-a3.y);
    float2 b0 = make_float2(t0.x+t2.x, t0.y+t2.y);
    float2 b2 = make_float2(t0.x-t2.x, t0.y-t2.y);
    float2 b1, b3;
    if (DIR < 0) {  // forward: w4 = -i
      b1 = make_float2(t1.x + t3.y, t1.y - t3.x);
      b3 = make_float2(t1.x - t3.y, t1.y + t3.x);
    } else {
      b1 = make_float2(t1.x - t3.y, t1.y + t3.x);
      b3 = make_float2(t1.x + t3.y, t1.y - t3.x);
    }
    float sn, cn;
    __sincosf(theta * (float)p, &sn, &cn);
    float2 w1 = make_float2(cn, sn);
    float2 w2 = cmulf(w1, w1);
    float2 w3 = cmulf(w2, w1);
    int base = 4*u - 3*q;
    Y[base]       = b0;
    Y[base + S]   = cmulf(b1, w1);
    Y[base + 2*S] = cmulf(b2, w2);
    Y[base + 3*S] = cmulf(b3, w3);
  }
}

template<int DIR>
__device__ __forceinline__ void radix2_stage(const float2* __restrict__ X, float2* __restrict__ Y, int lane)
{
  const float theta = (float)DIR * 6.2831853071795864769f / 6.0f;
#pragma unroll
  for (int k = 0; k < 6; ++k) {
    int u = lane + 32*k;
    int p = u >> 6;
    int q = u & 63;
    float2 a0 = X[u], a1 = X[u+192];
    float2 b0 = make_float2(a0.x+a1.x, a0.y+a1.y);
    float2 d  = make_float2(a0.x-a1.x, a0.y-a1.y);
    float sn, cn;
    __sincosf(theta * (float)p, &sn, &cn);
    int base = 2*u - q;
    Y[base]      = b0;
    Y[base + 64] = cmulf(d, make_float2(cn, sn));
  }
}

template<int DIR>
__device__ __forceinline__ void radix3_stage(const float2* __restrict__ X, float2* __restrict__ Y, int lane)
{
  const float SQ = (DIR < 0) ? -0.86602540378443864676f : 0.86602540378443864676f;
#pragma unroll
  for (int k = 0; k < 4; ++k) {
    int u = lane + 32*k;
    float2 a0 = X[u], a1 = X[u+128], a2 = X[u+256];
    float2 s12 = make_float2(a1.x+a2.x, a1.y+a2.y);
    float2 d12 = make_float2(a1.x-a2.x, a1.y-a2.y);
    float2 b0 = make_float2(a0.x+s12.x, a0.y+s12.y);
    float2 mm = make_float2(a0.x-0.5f*s12.x, a0.y-0.5f*s12.y);
    float2 e  = make_float2(-d12.y*SQ, d12.x*SQ);
    Y[u]     = b0;
    Y[u+128] = make_float2(mm.x+e.x, mm.y+e.y);
    Y[u+256] = make_float2(mm.x-e.x, mm.y-e.y);
  }
}

// Runs all 5 stages A->B->A->B->A->B. Result in B. Trailing __syncthreads included.
template<int DIR>
__device__ __forceinline__ void fft_stages(float2* Xr, float2* Yr, int lane)
{
  radix4_stage<DIR, 1, 384>(Xr, Yr, lane); __syncthreads();
  radix4_stage<DIR, 4,  96>(Yr, Xr, lane); __syncthreads();
  radix4_stage<DIR,16,  24>(Xr, Yr, lane); __syncthreads();
  radix2_stage<DIR>(Yr, Xr, lane);         __syncthreads();
  radix3_stage<DIR>(Xr, Yr, lane);         __syncthreads();
}

// ---------------- FFT kernels ----------------

// K1: tmp[b,c,h,:] = FFT_w( S[b,c,h,:] * p[b,h,:] )
__global__ __launch_bounds__(TPB) void k_row_fwd(
    const float2* __restrict__ p, const float* __restrict__ Sre,
    const float* __restrict__ Sim, float2* __restrict__ tmp)
{
  __shared__ float2 bufA[NROW*PITCH];
  __shared__ float2 bufB[NROW*PITCH];
  int tid = threadIdx.x;
  int tile = blockIdx.x % (Hn/NROW);
  int bc   = blockIdx.x / (Hn/NROW);
  int b = bc / Cn;
  int h0 = tile * NROW;
  for (int e = tid; e < NROW*Wn; e += TPB) {
    int r = e / Wn, col = e - r*Wn;
    int gi = (h0 + r)*Wn + col;
    float2 pv = p[b*NPIX + gi];
    float sr = Sre[(size_t)bc*NPIX + gi], si = Sim[(size_t)bc*NPIX + gi];
    bufA[r*PITCH + col] = make_float2(sr*pv.x - si*pv.y, sr*pv.y + si*pv.x);
  }
  __syncthreads();
  int row = tid >> 5, lane = tid & 31;
  fft_stages<-1>(bufA + row*PITCH, bufB + row*PITCH, lane);
  for (int e = tid; e < NROW*Wn; e += TPB) {
    int r = e / Wn, col = e - r*Wn;
    tmp[(size_t)bc*NPIX + (h0 + r)*Wn + col] = bufB[r*PITCH + col];
  }
}

// K2: column FFTs on an 8-column tile. FULL: fwd + mask*(1/(H*W)) + inv. else: inv only.
template<bool FULL>
__global__ __launch_bounds__(TPB) void k_col(
    float2* __restrict__ tmp, const float* __restrict__ mask)
{
  __shared__ float2 bufA[NROW*PITCH];
  __shared__ float2 bufB[NROW*PITCH];
  int tid = threadIdx.x;
  int tile = blockIdx.x % (Wn/NROW);
  int bc   = blockIdx.x / (Wn/NROW);
  int b = bc / Cn;
  int w0 = tile * NROW;
  for (int e = tid; e < NROW*Hn; e += TPB) {
    int wi = e & 7, h = e >> 3;
    bufA[wi*PITCH + h] = tmp[(size_t)bc*NPIX + h*Wn + w0 + wi];
  }
  __syncthreads();
  int row = tid >> 5, lane = tid & 31;
  float2* X = bufA + row*PITCH;
  float2* Y = bufB + row*PITCH;
  if (FULL) {
    fft_stages<-1>(X, Y, lane);                  // result in bufB
    const float SC = 1.0f / (float)NPIX;
    for (int e = tid; e < NROW*Hn; e += TPB) {
      int wi = e & 7, h = e >> 3;
      float mv = mask[b*NPIX + h*Wn + w0 + wi] * SC;
      float2 v = bufB[wi*PITCH + h];
      bufB[wi*PITCH + h] = make_float2(v.x*mv, v.y*mv);
    }
    __syncthreads();
    fft_stages<1>(Y, X, lane);                   // result in bufA
    for (int e = tid; e < NROW*Hn; e += TPB) {
      int wi = e & 7, h = e >> 3;
      tmp[(size_t)bc*NPIX + h*Wn + w0 + wi] = bufA[wi*PITCH + h];
    }
  } else {
    fft_stages<1>(X, Y, lane);                   // result in bufB
    for (int e = tid; e < NROW*Hn; e += TPB) {
      int wi = e & 7, h = e >> 3;
      tmp[(size_t)bc*NPIX + h*Wn + w0 + wi] = bufB[wi*PITCH + h];
    }
  }
}

// K3 (atomic-free): partial[g,b] = sum_{c in group g} conj(S[b,c]) * IFFT_w(tmp[b,c])
// Each block: one (b, g, row-tile); accumulates CPG coils in registers; one coalesced store.
__global__ __launch_bounds__(TPB) void k_row_inv_acc(
    const float2* __restrict__ tmp, const float* __restrict__ Sre,
    const float* __restrict__ Sim, float2* __restrict__ partial)
{
  __shared__ float2 bufA[NROW*PITCH];
  __shared__ float2 bufB[NROW*PITCH];
  int tid = threadIdx.x;
  int tile = blockIdx.x % (Hn/NROW);
  int rest = blockIdx.x / (Hn/NROW);
  int g = rest % GRP;
  int b = rest / GRP;
  int h0 = tile * NROW;
  int row = tid >> 5, lane = tid & 31;

  float accx[12], accy[12];
#pragma unroll
  for (int k = 0; k < 12; ++k) { accx[k] = 0.0f; accy[k] = 0.0f; }

  for (int j = 0; j < CPG; ++j) {
    int c = g*CPG + j;
    size_t bc = (size_t)b*Cn + c;
    for (int e = tid; e < NROW*Wn; e += TPB) {
      int r = e / Wn, col = e - r*Wn;
      bufA[r*PITCH + col] = tmp[bc*NPIX + (h0 + r)*Wn + col];
    }
    __syncthreads();
    fft_stages<1>(bufA + row*PITCH, bufB + row*PITCH, lane);
#pragma unroll
    for (int k = 0; k < 12; ++k) {
      int e = tid + 256*k;
      int r = e / Wn, col = e - r*Wn;
      int gi = (h0 + r)*Wn + col;
      float2 v = bufB[r*PITCH + col];
      float sr = Sre[bc*NPIX + gi], si = Sim[bc*NPIX + gi];
      accx[k] += sr*v.x + si*v.y;
      accy[k] += sr*v.y - si*v.x;
    }
    __syncthreads();  // protect bufB before next coil's stages write it
  }

  size_t pbase = ((size_t)g*Bn + b)*NPIX;
#pragma unroll
  for (int k = 0; k < 12; ++k) {
    int e = tid + 256*k;
    int r = e / Wn, col = e - r*Wn;
    partial[pbase + (h0 + r)*Wn + col] = make_float2(accx[k], accy[k]);
  }
}

// ---------------- elementwise / CG kernels ----------------

__global__ __launch_bounds__(TPB) void k_pre(
    const float* __restrict__ yre, const float* __restrict__ yim,
    const float* __restrict__ mask, float2* __restrict__ tmp)
{
  size_t i = (size_t)blockIdx.x*TPB + threadIdx.x;
  if (i >= (size_t)Bn*Cn*NPIX) return;
  size_t bc = i / NPIX; size_t b = bc / Cn; size_t pix = i - bc*NPIX;
  float m = mask[b*NPIX + pix] * (1.0f/384.0f);
  tmp[i] = make_float2(yre[i]*m, yim[i]*m);
}

__global__ void k_zero_scal(float* __restrict__ scal)
{
  int i = threadIdx.x;
  if (i < 96) scal[i] = 0.0f;
}

__device__ __forceinline__ void block_reduce_atomic(float sum, float* target)
{
  __shared__ float red[TPB];
  red[threadIdx.x] = sum; __syncthreads();
  for (int s = TPB/2; s > 0; s >>= 1) {
    if (threadIdx.x < s) red[threadIdx.x] += red[threadIdx.x + s];
    __syncthreads();
  }
  if (threadIdx.x == 0) unsafeAtomicAdd(target, red[0]);
}

// rhs combine + CG init: rv = lambda*x_in + sum_g partial[g]; r=p=rv; x=0; rTr0=sum|rv|^2
__global__ __launch_bounds__(TPB) void k_rhs_init(
    const float* __restrict__ xre, const float* __restrict__ xim,
    const float* __restrict__ lam, const float2* __restrict__ partial,
    float2* __restrict__ r, float2* __restrict__ p, float2* __restrict__ x,
    float* __restrict__ scal)
{
  int b = blockIdx.y;
  float l = lam[0];
  float sum = 0.0f;
  for (int i = blockIdx.x*TPB + threadIdx.x; i < NPIX; i += RED_BLKS*TPB) {
    size_t gi = (size_t)b*NPIX + i;
    float2 rv = make_float2(l*xre[gi], l*xim[gi]);
#pragma unroll
    for (int g = 0; g < GRP; ++g) {
      float2 pv = partial[((size_t)g*Bn + b)*NPIX + i];
      rv.x += pv.x; rv.y += pv.y;
    }
    r[gi] = rv; p[gi] = rv;
    x[gi] = make_float2(0.0f, 0.0f);
    sum += rv.x*rv.x + rv.y*rv.y;
  }
  block_reduce_atomic(sum, &scal[b]);
}

// Ap = lambda*p + sum_g partial[g];  pAp = sum p.Ap
__global__ __launch_bounds__(TPB) void k_combine_dot(
    const float2* __restrict__ p, const float* __restrict__ lam,
    const float2* __restrict__ partial, float2* __restrict__ Ap,
    float* __restrict__ slot)
{
  int b = blockIdx.y;
  float l = lam[0];
  float sum = 0.0f;
  for (int i = blockIdx.x*TPB + threadIdx.x; i < NPIX; i += RED_BLKS*TPB) {
    size_t gi = (size_t)b*NPIX + i;
    float2 pv = p[gi];
    float2 av = make_float2(l*pv.x, l*pv.y);
#pragma unroll
    for (int g = 0; g < GRP; ++g) {
      float2 qv = partial[((size_t)g*Bn + b)*NPIX + i];
      av.x += qv.x; av.y += qv.y;
    }
    Ap[gi] = av;
    sum += pv.x*av.x + pv.y*av.y;
  }
  block_reduce_atomic(sum, &slot[b]);
}

// x += alpha p; r -= alpha Ap; rTr_new = sum|r|^2  (frozen if rTr <= TOL)
__global__ __launch_bounds__(TPB) void k_upd1(
    float2* __restrict__ x, float2* __restrict__ r,
    const float2* __restrict__ p, const float2* __restrict__ Ap,
    const float* __restrict__ rtr_cur, float* __restrict__ rtr_new,
    const float* __restrict__ pap)
{
  int b = blockIdx.y;
  float rtr = rtr_cur[b];
  bool act = rtr > TOLF;
  float alpha = act ? rtr / pap[b] : 0.0f;
  float sum = 0.0f;
  for (int i = blockIdx.x*TPB + threadIdx.x; i < NPIX; i += RED_BLKS*TPB) {
    size_t gi = (size_t)b*NPIX + i;
    float2 rv = r[gi];
    if (act) {
      float2 pv = p[gi], av = Ap[gi], xv = x[gi];
      xv.x += alpha*pv.x; xv.y += alpha*pv.y;
      rv.x -= alpha*av.x; rv.y -= alpha*av.y;
      x[gi] = xv; r[gi] = rv;
    }
    sum += rv.x*rv.x + rv.y*rv.y;
  }
  block_reduce_atomic(sum, &rtr_new[b]);
}

// p = r + beta p (if active)
__global__ __launch_bounds__(TPB) void k_upd2(
    float2* __restrict__ p, const float2* __restrict__ r,
    const float* __restrict__ rtr_cur, const float* __restrict__ rtr_new)
{
  int b = blockIdx.y;
  float rtr = rtr_cur[b];
  bool act = rtr > TOLF;
  if (!act) return;
  float beta = rtr_new[b] / rtr;
  for (int i = blockIdx.x*TPB + threadIdx.x; i < NPIX; i += RED_BLKS*TPB) {
    size_t gi = (size_t)b*NPIX + i;
    float2 rv = r[gi];
    float2 pv = p[gi];
    p[gi] = make_float2(rv.x + beta*pv.x, rv.y + beta*pv.y);
  }
}

// ---------------- launch ----------------

extern "C" void kernel_launch(void* const* d_in, const int* in_sizes, int n_in,
                              void* d_out, int out_size, void* d_ws, size_t ws_size,
                              hipStream_t stream)
{
  const float* lam  = (const float*)d_in[0];
  const float* xre  = (const float*)d_in[1];
  const float* xim  = (const float*)d_in[2];
  const float* yre  = (const float*)d_in[3];
  const float* yim  = (const float*)d_in[4];
  const float* sre  = (const float*)d_in[5];
  const float* sim  = (const float*)d_in[6];
  const float* mask = (const float*)d_in[7];

  char* ws = (char*)d_ws;
  float2* tmp  = (float2*)ws;  ws += (size_t)Bn*Cn*NPIX*sizeof(float2);
  float2* part = (float2*)ws;  ws += (size_t)GRP*Bn*NPIX*sizeof(float2);
  float2* r    = (float2*)ws;  ws += (size_t)Bn*NPIX*sizeof(float2);
  float2* p    = (float2*)ws;  ws += (size_t)Bn*NPIX*sizeof(float2);
  float2* Ap   = (float2*)ws;  ws += (size_t)Bn*NPIX*sizeof(float2);
  float*  scal = (float*)ws;   // rTr[11][B] at [0..43], pAp[10][B] at [44..83]
  float2* x    = (float2*)d_out;

  dim3 blk(TPB);
  dim3 rg(RED_BLKS, Bn);
  int grid_fft_row = Bn*Cn*(Hn/NROW);       // 3072
  int grid_fft_col = Bn*Cn*(Wn/NROW);       // 3072
  int grid_inv     = Bn*GRP*(Hn/NROW);      // 768

  k_zero_scal<<<1, 128, 0, stream>>>(scal);

  // ---- rhs = AH(y) + lambda*x ----
  k_pre<<<(Bn*Cn*NPIX)/TPB, blk, 0, stream>>>(yre, yim, mask, tmp);
  k_col<false><<<grid_fft_col, blk, 0, stream>>>(tmp, mask);
  k_row_inv_acc<<<grid_inv, blk, 0, stream>>>(tmp, sre, sim, part);
  k_rhs_init<<<rg, blk, 0, stream>>>(xre, xim, lam, part, r, p, x, scal);

  for (int it = 0; it < NITER; ++it) {
    k_row_fwd<<<grid_fft_row, blk, 0, stream>>>(p, sre, sim, tmp);
    k_col<true><<<grid_fft_col, blk, 0, stream>>>(tmp, mask);
    k_row_inv_acc<<<grid_inv, blk, 0, stream>>>(tmp, sre, sim, part);
    k_combine_dot<<<rg, blk, 0, stream>>>(p, lam, part, Ap, scal + 44 + it*Bn);
    k_upd1<<<rg, blk, 0, stream>>>(x, r, p, Ap, scal + it*Bn, scal + (it+1)*Bn, scal + 44 + it*Bn);
    if (it < NITER-1)
      k_upd2<<<rg, blk, 0, stream>>>(p, r, scal + it*Bn, scal + (it+1)*Bn);
  }
}

// Round 3
// 1622.434 us; speedup vs baseline: 1.9604x; 1.5965x over previous
//
#include <hip/hip_runtime.h>

// CG-SENSE: B=4, C=16, H=W=384. fp32. x lives in d_out (float2 == [.,2]).
// FFT-384 = wave-synchronous four-step: in-register FFT-12 (lane holds 12 regs,
// x[32*n1+lane]) * twiddle * cross-lane FFT-32 via ds_swizzle (radix-2 DIF,
// bit-reversed lane output). Unscramble through LDS with 13-stride layout:
// value at natural index w lives at LDS offset w + w/12 (== 13*(w/12) + w%12).

#define Bn 4
#define Cn 16
#define Hn 384
#define Wn 384
#define NPIX (Hn*Wn)
#define TPB 256
#define TOLF 1e-10f
#define NITER 10
#define RED_BLKS 72
#define GRP 4
#define CPG (Cn/GRP)
#define RPITCH 416   // row-kernel LDS pitch (float2); max offset 414
#define CPITCH 420   // col-kernel LDS pitch

__device__ __forceinline__ float2 cadd(float2 a, float2 b){ return make_float2(a.x+b.x, a.y+b.y); }
__device__ __forceinline__ float2 csub(float2 a, float2 b){ return make_float2(a.x-b.x, a.y-b.y); }
__device__ __forceinline__ float2 cmulf(float2 a, float2 b){
  return make_float2(a.x*b.x - a.y*b.y, a.x*b.y + a.y*b.x);
}

// wave-local LDS fence: drain DS queue + stop compiler reordering. DS ops are
// in-order per wave, so write->fence->read within a wave is safe without s_barrier.
__device__ __forceinline__ void wave_fence(){ asm volatile("s_waitcnt lgkmcnt(0)" ::: "memory"); }

// cross-lane xor within 32-lane groups (BitMode swizzle imm)
template<int IMM>
__device__ __forceinline__ float2 shx(float2 v){
  int x = __builtin_amdgcn_ds_swizzle(__float_as_int(v.x), IMM);
  int y = __builtin_amdgcn_ds_swizzle(__float_as_int(v.y), IMM);
  return make_float2(__int_as_float(x), __int_as_float(y));
}

__device__ __forceinline__ int rev5(int x){
  return ((x&1)<<4) | ((x&2)<<2) | (x&4) | ((x&8)>>2) | ((x&16)>>4);
}

__device__ __forceinline__ int offmap(int w){ return w + ((w*683)>>13); }  // w + w/12, w<384

// ---- in-register FFT-12 over v[n1] (natural in, natural out). 12 = 3x4 ----
template<int DIR>
__device__ __forceinline__ void fft12(float2* v)
{
  const float S3 = (DIR<0) ? -0.86602540378443864676f : 0.86602540378443864676f;
  const float sg = (DIR<0) ? -1.f : 1.f;
  float2 t[4][3];
#pragma unroll
  for (int b = 0; b < 4; ++b) {
    float2 a0 = v[b], a1 = v[4+b], a2 = v[8+b];
    float2 s = cadd(a1,a2), d = csub(a1,a2);
    float2 mm = make_float2(a0.x - 0.5f*s.x, a0.y - 0.5f*s.y);
    float2 e  = make_float2(-d.y*S3, d.x*S3);
    t[b][0] = cadd(a0,s);
    t[b][1] = cadd(mm,e);
    t[b][2] = csub(mm,e);
  }
  const float2 w1  = make_float2(0.86602540378443864676f, sg*0.5f);
  const float2 w2  = make_float2(0.5f, sg*0.86602540378443864676f);
  const float2 w3  = make_float2(0.f, sg);
  const float2 w4t = make_float2(-0.5f, sg*0.86602540378443864676f);
  const float2 w6  = make_float2(-1.f, 0.f);
  t[1][1] = cmulf(t[1][1], w1);  t[1][2] = cmulf(t[1][2], w2);
  t[2][1] = cmulf(t[2][1], w2);  t[2][2] = cmulf(t[2][2], w4t);
  t[3][1] = cmulf(t[3][1], w3);  t[3][2] = cmulf(t[3][2], w6);
#pragma unroll
  for (int c = 0; c < 3; ++c) {
    float2 e = cadd(t[0][c], t[2][c]);
    float2 f = csub(t[0][c], t[2][c]);
    float2 g = cadd(t[1][c], t[3][c]);
    float2 h = csub(t[1][c], t[3][c]);
    float2 ih = (DIR<0) ? make_float2(h.y, -h.x) : make_float2(-h.y, h.x);  // -i*h (fwd) / +i*h (inv)
    v[c]   = cadd(e,g);
    v[c+3] = cadd(f,ih);
    v[c+6] = csub(e,g);
    v[c+9] = csub(f,ih);
  }
}

// ---- cross-lane FFT-32 over lanes (natural lane in, bit-reversed lane out) ----
template<int DIR>
__device__ __forceinline__ void fft32_lanes(float2* v, int li)
{
  const float c2pi = (DIR<0) ? -6.2831853071795864769f : 6.2831853071795864769f;
  const float sg   = (DIR<0) ? -1.f : 1.f;
  float s, c;
  __sincosf(c2pi*(1.f/32.f)*(float)(li&15), &s, &c); float2 wA = make_float2(c,s);
  __sincosf(c2pi*(1.f/16.f)*(float)(li&7),  &s, &c); float2 wB = make_float2(c,s);
  __sincosf(c2pi*(1.f/ 8.f)*(float)(li&3),  &s, &c); float2 wC = make_float2(c,s);
  bool bA = li & 16, bB = li & 8, bC = li & 4, bD = li & 2, bE = li & 1;
#pragma unroll
  for (int k = 0; k < 12; ++k) {
    float2 a = v[k], o;
    o = shx<0x401F>(a); a = bA ? cmulf(csub(o,a), wA) : cadd(a,o);
    o = shx<0x201F>(a); a = bB ? cmulf(csub(o,a), wB) : cadd(a,o);
    o = shx<0x101F>(a); a = bC ? cmulf(csub(o,a), wC) : cadd(a,o);
    o = shx<0x081F>(a);
    { float2 su = cadd(a,o), d = csub(o,a);
      float2 dw = bE ? make_float2(-sg*d.y, sg*d.x) : d;   // * w4^(li&1)
      a = bD ? dw : su; }
    o = shx<0x041F>(a); a = bE ? csub(o,a) : cadd(a,o);
    v[k] = a;
  }
}

// Full 384-pt FFT. In: reg k = x[32k+li]. Out: reg k1 = X[k1 + 12*rev5(li)].
template<int DIR>
__device__ __forceinline__ void fft384(float2* v, int li)
{
  fft12<DIR>(v);
  const float c2pi = (DIR<0) ? -6.2831853071795864769f : 6.2831853071795864769f;
  float s, c;
  __sincosf(c2pi*(1.f/384.f)*(float)li, &s, &c);
  float2 W = make_float2(c,s), cw = W;
#pragma unroll
  for (int k = 1; k < 12; ++k) { v[k] = cmulf(v[k], cw); cw = cmulf(cw, W); }
  fft32_lanes<DIR>(v, li);
}

// ---------------- FFT kernels (no __syncthreads in row kernels) ----------------

// tmp[b,c,h,:] = FFT_w( S[b,c,h,:] * p[b,h,:] )   (unnormalized fwd)
__global__ __launch_bounds__(TPB) void k_row_fwd(
    const float2* __restrict__ p, const float* __restrict__ Sre,
    const float* __restrict__ Sim, float2* __restrict__ tmp)
{
  __shared__ float2 lbuf[8*RPITCH];
  int tid = threadIdx.x;
  int wave = tid>>6, lane = tid&63, sub = lane>>5, li = lane&31;
  int row = wave*2 + sub;
  int tile = blockIdx.x % (Hn/8);
  int bc   = blockIdx.x / (Hn/8);
  int b = bc / Cn;
  int h = tile*8 + row;
  size_t gbase = (size_t)bc*NPIX + (size_t)h*Wn;
  size_t pbase = (size_t)b*NPIX + (size_t)h*Wn;

  float2 v[12];
#pragma unroll
  for (int k = 0; k < 12; ++k) {
    int w = 32*k + li;
    float2 pv = p[pbase + w];
    float sr = Sre[gbase + w], si = Sim[gbase + w];
    v[k] = make_float2(sr*pv.x - si*pv.y, sr*pv.y + si*pv.x);
  }
  fft384<-1>(v, li);
  int m = rev5(li);
  float2* lrow = lbuf + row*RPITCH;
#pragma unroll
  for (int k = 0; k < 12; ++k) lrow[13*m + k] = v[k];
  wave_fence();
#pragma unroll
  for (int k = 0; k < 12; ++k) {
    int w = 32*k + li;
    tmp[gbase + w] = lrow[offmap(w)];
  }
}

// partial[g,b] = sum_{c in g} conj(S[b,c]) * IFFT_w(tmp[b,c])   (unnormalized inv)
__global__ __launch_bounds__(TPB) void k_row_inv_acc(
    const float2* __restrict__ tmp, const float* __restrict__ Sre,
    const float* __restrict__ Sim, float2* __restrict__ partial)
{
  __shared__ float2 lbuf[8*RPITCH];
  int tid = threadIdx.x;
  int wave = tid>>6, lane = tid&63, sub = lane>>5, li = lane&31;
  int row = wave*2 + sub;
  int tile = blockIdx.x % (Hn/8);
  int rest = blockIdx.x / (Hn/8);
  int g = rest % GRP;
  int b = rest / GRP;
  int h = tile*8 + row;
  int m = rev5(li);
  float2* lrow = lbuf + row*RPITCH;

  float2 acc[12];
#pragma unroll
  for (int k = 0; k < 12; ++k) acc[k] = make_float2(0.f, 0.f);

  for (int j = 0; j < CPG; ++j) {
    size_t bc = (size_t)b*Cn + (g*CPG + j);
    size_t gbase = bc*NPIX + (size_t)h*Wn;
    float2 v[12];
#pragma unroll
    for (int k = 0; k < 12; ++k) v[k] = tmp[gbase + 32*k + li];
    fft384<1>(v, li);
    wave_fence();                       // drain prior coil's gather reads (WAR)
#pragma unroll
    for (int k = 0; k < 12; ++k) lrow[13*m + k] = v[k];
    wave_fence();                       // writes visible before gather (RAW)
#pragma unroll
    for (int k = 0; k < 12; ++k) {
      int w = 32*k + li;
      float2 u = lrow[offmap(w)];
      float sr = Sre[gbase + w], si = Sim[gbase + w];
      acc[k].x += sr*u.x + si*u.y;
      acc[k].y += sr*u.y - si*u.x;
    }
  }
  size_t pbase = ((size_t)g*Bn + b)*NPIX + (size_t)h*Wn;
#pragma unroll
  for (int k = 0; k < 12; ++k) partial[pbase + 32*k + li] = acc[k];
}

// column pass, FULL: fwd FFT_h, * mask/(H*W), inv FFT_h. 8 columns per block.
__global__ __launch_bounds__(TPB) void k_col_full(
    float2* __restrict__ tmp, const float* __restrict__ mask)
{
  __shared__ float2 dbuf[8*CPITCH];
  __shared__ float  mbuf[8*CPITCH];
  int tid = threadIdx.x;
  int wave = tid>>6, lane = tid&63, sub = lane>>5, li = lane&31;
  int col = wave*2 + sub;
  int tile = blockIdx.x % (Wn/8);
  int bc   = blockIdx.x / (Wn/8);
  int b = bc / Cn;
  int w0 = tile*8;
  size_t tbase = (size_t)bc*NPIX;
  size_t mbase = (size_t)b*NPIX;

  for (int e = tid; e < 8*Hn; e += TPB) {
    int wi = e & 7, h = e >> 3;
    int off = offmap(h);
    dbuf[wi*CPITCH + off] = tmp[tbase + (size_t)h*Wn + w0 + wi];
    mbuf[wi*CPITCH + off] = mask[mbase + (size_t)h*Wn + w0 + wi];
  }
  __syncthreads();

  float2* drow = dbuf + col*CPITCH;
  float*  mrow = mbuf + col*CPITCH;
  int m = rev5(li);
  float2 v[12];
#pragma unroll
  for (int k = 0; k < 12; ++k) v[k] = drow[offmap(32*k + li)];
  fft384<-1>(v, li);
  const float SC = 1.0f / (float)NPIX;
#pragma unroll
  for (int k = 0; k < 12; ++k) {              // k-space h index = k + 12*m
    float mv = mrow[13*m + k] * SC;
    v[k] = make_float2(v[k].x*mv, v[k].y*mv);
  }
  wave_fence();
#pragma unroll
  for (int k = 0; k < 12; ++k) drow[13*m + k] = v[k];   // unscramble store
  wave_fence();
#pragma unroll
  for (int k = 0; k < 12; ++k) v[k] = drow[offmap(32*k + li)];  // natural reload
  fft384<1>(v, li);
  wave_fence();
#pragma unroll
  for (int k = 0; k < 12; ++k) drow[13*m + k] = v[k];
  __syncthreads();

  for (int e = tid; e < 8*Hn; e += TPB) {
    int wi = e & 7, h = e >> 3;
    tmp[tbase + (size_t)h*Wn + w0 + wi] = dbuf[wi*CPITCH + offmap(h)];
  }
}

// rhs column pass: stage y*mask*(1/384), inverse column FFT only.
__global__ __launch_bounds__(TPB) void k_col_rhs(
    const float* __restrict__ yre, const float* __restrict__ yim,
    const float* __restrict__ mask, float2* __restrict__ tmp)
{
  __shared__ float2 dbuf[8*CPITCH];
  int tid = threadIdx.x;
  int wave = tid>>6, lane = tid&63, sub = lane>>5, li = lane&31;
  int col = wave*2 + sub;
  int tile = blockIdx.x % (Wn/8);
  int bc   = blockIdx.x / (Wn/8);
  int b = bc / Cn;
  int w0 = tile*8;
  size_t tbase = (size_t)bc*NPIX;
  size_t mbase = (size_t)b*NPIX;

  for (int e = tid; e < 8*Hn; e += TPB) {
    int wi = e & 7, h = e >> 3;
    size_t gi = (size_t)h*Wn + w0 + wi;
    float mv = mask[mbase + gi] * (1.0f/384.0f);
    dbuf[wi*CPITCH + offmap(h)] = make_float2(yre[tbase+gi]*mv, yim[tbase+gi]*mv);
  }
  __syncthreads();

  float2* drow = dbuf + col*CPITCH;
  int m = rev5(li);
  float2 v[12];
#pragma unroll
  for (int k = 0; k < 12; ++k) v[k] = drow[offmap(32*k + li)];
  fft384<1>(v, li);
  wave_fence();
#pragma unroll
  for (int k = 0; k < 12; ++k) drow[13*m + k] = v[k];
  __syncthreads();

  for (int e = tid; e < 8*Hn; e += TPB) {
    int wi = e & 7, h = e >> 3;
    tmp[tbase + (size_t)h*Wn + w0 + wi] = dbuf[wi*CPITCH + offmap(h)];
  }
}

// ---------------- CG scalar/vector kernels ----------------

__global__ void k_zero_scal(float* __restrict__ scal)
{
  int i = threadIdx.x;
  if (i < 96) scal[i] = 0.0f;
}

__device__ __forceinline__ void block_reduce_atomic(float sum, float* target)
{
  __shared__ float red[TPB];
  red[threadIdx.x] = sum; __syncthreads();
  for (int s = TPB/2; s > 0; s >>= 1) {
    if (threadIdx.x < s) red[threadIdx.x] += red[threadIdx.x + s];
    __syncthreads();
  }
  if (threadIdx.x == 0) unsafeAtomicAdd(target, red[0]);
}

__global__ __launch_bounds__(TPB) void k_rhs_init(
    const float* __restrict__ xre, const float* __restrict__ xim,
    const float* __restrict__ lam, const float2* __restrict__ partial,
    float2* __restrict__ r, float2* __restrict__ p, float2* __restrict__ x,
    float* __restrict__ scal)
{
  int b = blockIdx.y;
  float l = lam[0];
  float sum = 0.0f;
  for (int i = blockIdx.x*TPB + threadIdx.x; i < NPIX; i += RED_BLKS*TPB) {
    size_t gi = (size_t)b*NPIX + i;
    float2 rv = make_float2(l*xre[gi], l*xim[gi]);
#pragma unroll
    for (int g = 0; g < GRP; ++g) {
      float2 pv = partial[((size_t)g*Bn + b)*NPIX + i];
      rv.x += pv.x; rv.y += pv.y;
    }
    r[gi] = rv; p[gi] = rv;
    x[gi] = make_float2(0.0f, 0.0f);
    sum += rv.x*rv.x + rv.y*rv.y;
  }
  block_reduce_atomic(sum, &scal[b]);
}

__global__ __launch_bounds__(TPB) void k_combine_dot(
    const float2* __restrict__ p, const float* __restrict__ lam,
    const float2* __restrict__ partial, float2* __restrict__ Ap,
    float* __restrict__ slot)
{
  int b = blockIdx.y;
  float l = lam[0];
  float sum = 0.0f;
  for (int i = blockIdx.x*TPB + threadIdx.x; i < NPIX; i += RED_BLKS*TPB) {
    size_t gi = (size_t)b*NPIX + i;
    float2 pv = p[gi];
    float2 av = make_float2(l*pv.x, l*pv.y);
#pragma unroll
    for (int g = 0; g < GRP; ++g) {
      float2 qv = partial[((size_t)g*Bn + b)*NPIX + i];
      av.x += qv.x; av.y += qv.y;
    }
    Ap[gi] = av;
    sum += pv.x*av.x + pv.y*av.y;
  }
  block_reduce_atomic(sum, &slot[b]);
}

__global__ __launch_bounds__(TPB) void k_upd1(
    float2* __restrict__ x, float2* __restrict__ r,
    const float2* __restrict__ p, const float2* __restrict__ Ap,
    const float* __restrict__ rtr_cur, float* __restrict__ rtr_new,
    const float* __restrict__ pap)
{
  int b = blockIdx.y;
  float rtr = rtr_cur[b];
  bool act = rtr > TOLF;
  float alpha = act ? rtr / pap[b] : 0.0f;
  float sum = 0.0f;
  for (int i = blockIdx.x*TPB + threadIdx.x; i < NPIX; i += RED_BLKS*TPB) {
    size_t gi = (size_t)b*NPIX + i;
    float2 rv = r[gi];
    if (act) {
      float2 pv = p[gi], av = Ap[gi], xv = x[gi];
      xv.x += alpha*pv.x; xv.y += alpha*pv.y;
      rv.x -= alpha*av.x; rv.y -= alpha*av.y;
      x[gi] = xv; r[gi] = rv;
    }
    sum += rv.x*rv.x + rv.y*rv.y;
  }
  block_reduce_atomic(sum, &rtr_new[b]);
}

__global__ __launch_bounds__(TPB) void k_upd2(
    float2* __restrict__ p, const float2* __restrict__ r,
    const float* __restrict__ rtr_cur, const float* __restrict__ rtr_new)
{
  int b = blockIdx.y;
  float rtr = rtr_cur[b];
  if (!(rtr > TOLF)) return;
  float beta = rtr_new[b] / rtr;
  for (int i = blockIdx.x*TPB + threadIdx.x; i < NPIX; i += RED_BLKS*TPB) {
    size_t gi = (size_t)b*NPIX + i;
    float2 rv = r[gi];
    float2 pv = p[gi];
    p[gi] = make_float2(rv.x + beta*pv.x, rv.y + beta*pv.y);
  }
}

// ---------------- launch ----------------

extern "C" void kernel_launch(void* const* d_in, const int* in_sizes, int n_in,
                              void* d_out, int out_size, void* d_ws, size_t ws_size,
                              hipStream_t stream)
{
  const float* lam  = (const float*)d_in[0];
  const float* xre  = (const float*)d_in[1];
  const float* xim  = (const float*)d_in[2];
  const float* yre  = (const float*)d_in[3];
  const float* yim  = (const float*)d_in[4];
  const float* sre  = (const float*)d_in[5];
  const float* sim  = (const float*)d_in[6];
  const float* mask = (const float*)d_in[7];

  char* ws = (char*)d_ws;
  float2* tmp  = (float2*)ws;  ws += (size_t)Bn*Cn*NPIX*sizeof(float2);
  float2* part = (float2*)ws;  ws += (size_t)GRP*Bn*NPIX*sizeof(float2);
  float2* r    = (float2*)ws;  ws += (size_t)Bn*NPIX*sizeof(float2);
  float2* p    = (float2*)ws;  ws += (size_t)Bn*NPIX*sizeof(float2);
  float2* Ap   = (float2*)ws;  ws += (size_t)Bn*NPIX*sizeof(float2);
  float*  scal = (float*)ws;   // rTr[11][B] at [0..43], pAp[10][B] at [44..83]
  float2* x    = (float2*)d_out;

  dim3 blk(TPB);
  dim3 rg(RED_BLKS, Bn);
  int grid_row = Bn*Cn*(Hn/8);   // 3072
  int grid_col = Bn*Cn*(Wn/8);   // 3072
  int grid_inv = Bn*GRP*(Hn/8);  // 768

  k_zero_scal<<<1, 128, 0, stream>>>(scal);

  // ---- rhs = AH(y) + lambda*x ----
  k_col_rhs<<<grid_col, blk, 0, stream>>>(yre, yim, mask, tmp);
  k_row_inv_acc<<<grid_inv, blk, 0, stream>>>(tmp, sre, sim, part);
  k_rhs_init<<<rg, blk, 0, stream>>>(xre, xim, lam, part, r, p, x, scal);

  for (int it = 0; it < NITER; ++it) {
    k_row_fwd<<<grid_row, blk, 0, stream>>>(p, sre, sim, tmp);
    k_col_full<<<grid_col, blk, 0, stream>>>(tmp, mask);
    k_row_inv_acc<<<grid_inv, blk, 0, stream>>>(tmp, sre, sim, part);
    k_combine_dot<<<rg, blk, 0, stream>>>(p, lam, part, Ap, scal + 44 + it*Bn);
    k_upd1<<<rg, blk, 0, stream>>>(x, r, p, Ap, scal + it*Bn, scal + (it+1)*Bn, scal + 44 + it*Bn);
    if (it < NITER-1)
      k_upd2<<<rg, blk, 0, stream>>>(p, r, scal + it*Bn, scal + (it+1)*Bn);
  }
}